// Round 2
// baseline (272.782 us; speedup 1.0000x reference)
//
#include <hip/hip_runtime.h>

// MHA block on gfx950: qkv = x@Wa+ba; causal attention (static softmax); out = o@Wp+bp.
// B=4, L=2048, D=1024, H=16, Hd=64. bf16 MFMA 16x16x32, fp32 accumulation.
// R7: fix R6's 8-phase GEMM:
//  (1) PH sync = bare s_barrier. Removed asm lgkmcnt(0)+sched_barrier(0): they forced
//      full LDS-drain before ANY MFMA each phase (CU-wide serialization; 17% MfmaUtil).
//      Compiler-tracked ds_reads get fine-grained lgkmcnt(N) -> staggered MFMA start.
//  (2) MODE0 BN=192 -> grid 32x16=512 = exactly 2 full rounds at 1 block/CU (no tail).
//      B staged as BN/8 uniform 8-row chunks (3 gl_lds/wave, phase 3). vmcnt(7)/(6).
//  Races unchanged-safe: every region's reads complete (consuming MFMAs + phase-end
//  barrier) before the gl_lds that overwrites it issues; tile-end vmcnt asm keeps the
//  compiler memory fence so next-tile ds_reads can't hoist above staging retire.

typedef __attribute__((ext_vector_type(8))) short short8;   // 8 bf16
typedef __attribute__((ext_vector_type(4))) short s16x4;    // 4 bf16
typedef __attribute__((ext_vector_type(4))) float f32x4;    // MFMA C/D frag

#define DEVI __device__ __forceinline__

constexpr int NE = 1024, NH = 16, NB = 4, L = 2048;
constexpr int M = NB * L;       // 8192 tokens
constexpr int KD = 1024;        // GEMM K (both GEMMs)

DEVI unsigned f2bf(float f) {
    union { float f; unsigned u; } v; v.f = f;
    unsigned u = v.u;
    u += 0x7fffu + ((u >> 16) & 1u);   // RNE
    return u >> 16;
}
DEVI unsigned pack_bf2(float lo, float hi) {   // round-half-up, 2 floats -> 1 dword
    union { float f; unsigned u; } a, b; a.f = lo; b.f = hi;
    return ((a.u + 0x8000u) >> 16) | ((b.u + 0x8000u) & 0xffff0000u);
}

typedef const __attribute__((address_space(1))) void* gas_t;
typedef __attribute__((address_space(3))) void* las_t;
DEVI void gl_lds16(const void* g, void* l) {
    __builtin_amdgcn_global_load_lds((gas_t)g, (las_t)l, 16, 0, 0);
}

// ---------- fp32 -> bf16 bulk convert (x) ----------
__global__ void k_f32_to_bf16(const float* __restrict__ in,
                              unsigned short* __restrict__ out, int n8) {
    int i = blockIdx.x * blockDim.x + threadIdx.x;
    if (i >= n8) return;
    const float4* p = (const float4*)in + (size_t)i * 2;
    float4 a = p[0], b = p[1];
    short8 r;
    r[0] = f2bf(a.x); r[1] = f2bf(a.y); r[2] = f2bf(a.z); r[3] = f2bf(a.w);
    r[4] = f2bf(b.x); r[5] = f2bf(b.y); r[6] = f2bf(b.z); r[7] = f2bf(b.w);
    ((short8*)out)[i] = r;
}

// ---------- fp32 [R][C] -> bf16 [C][R] transpose-convert (weights) ----------
__global__ void k_transpose_bf16(const float* __restrict__ in,
                                 unsigned short* __restrict__ out, int R, int C) {
    __shared__ float t[32][33];
    int x = blockIdx.x * 32 + threadIdx.x;
    int y0 = blockIdx.y * 32;
#pragma unroll
    for (int i = 0; i < 4; i++)
        t[threadIdx.y + 8 * i][threadIdx.x] = in[(size_t)(y0 + threadIdx.y + 8 * i) * C + x];
    __syncthreads();
    int xo = y0 + threadIdx.x;
    int yo = blockIdx.x * 32 + threadIdx.y;
#pragma unroll
    for (int i = 0; i < 4; i++)
        out[(size_t)(yo + 8 * i) * R + xo] = f2bf(t[threadIdx.x][threadIdx.y + 8 * i]);
}

// ---------- 8-phase 256-tile bf16 GEMM ----------
// LDS slot s of row r holds global k-seg s^(r&7) (seg = 16B = 8 bf16).
// A: 3 rotating regions [2 halves][128][64]; B: 2 regions [BN][64].

#define RD_A(ROFF, SWZ)                                              \
    _Pragma("unroll") for (int mt = 0; mt < 4; mt++)                 \
        af[mt] = *(const short8*)&aCur[((ROFF) + mt * 16 + l16) * 64 + (SWZ)];

#define RD_B(BF, SWZ)                                                \
    _Pragma("unroll") for (int nt = 0; nt < NF; nt++)                \
        BF[nt] = *(const short8*)&bCur[(bro + nt * 16 + l16) * 64 + (SWZ)];

#define MFMA_CLU(MH4, BF)                                            \
    __builtin_amdgcn_s_setprio(1);                                   \
    _Pragma("unroll") for (int mt = 0; mt < 4; mt++)                 \
    _Pragma("unroll") for (int nt = 0; nt < NF; nt++)                \
        acc[(MH4) + mt][nt] = __builtin_amdgcn_mfma_f32_16x16x32_bf16( \
            af[mt], BF[nt], acc[(MH4) + mt][nt], 0, 0, 0);           \
    __builtin_amdgcn_s_setprio(0);

#define VM_WAIT_STEADY                                               \
    if (MODE == 0) asm volatile("s_waitcnt vmcnt(7)" ::: "memory");  \
    else           asm volatile("s_waitcnt vmcnt(6)" ::: "memory");

#define GTILE(KT, CA, CA2, PAR, DOPRE)                               \
  {                                                                  \
    const short* aCur = &As3[(CA) * 16384 + wg_m * 8192];            \
    const short* bCur = &Bs[(PAR) * (BN * 64)];                      \
    /* phase 0: Mlo x kc0 */                                         \
    RD_A(0, swz0)                                                    \
    RD_B(bf0, swz0)                                                  \
    if (DOPRE) stA((KT) + 2, 0, (CA2));                              \
    __builtin_amdgcn_s_barrier();                                    \
    MFMA_CLU(0, bf0)                                                 \
    __builtin_amdgcn_s_barrier();                                    \
    /* phase 1: Mhi x kc0 */                                         \
    RD_A(64, swz0)                                                   \
    if (DOPRE) stA((KT) + 2, 1, (CA2));                              \
    __builtin_amdgcn_s_barrier();                                    \
    MFMA_CLU(4, bf0)                                                 \
    __builtin_amdgcn_s_barrier();                                    \
    /* phase 2: Mlo x kc1 */                                         \
    RD_A(0, swz1)                                                    \
    RD_B(bf1, swz1)                                                  \
    __builtin_amdgcn_s_barrier();                                    \
    MFMA_CLU(0, bf1)                                                 \
    __builtin_amdgcn_s_barrier();                                    \
    /* phase 3: Mhi x kc1; stage B(kt+2) AFTER last B(kt) read completed (ph2) */ \
    RD_A(64, swz1)                                                   \
    if (DOPRE) stB((KT) + 2, (PAR));                                 \
    __builtin_amdgcn_s_barrier();                                    \
    MFMA_CLU(4, bf1)                                                 \
    if (DOPRE) { VM_WAIT_STEADY }                                    \
    else       { asm volatile("s_waitcnt vmcnt(0)" ::: "memory"); }  \
    __builtin_amdgcn_s_barrier();                                    \
  }

template <int MODE>
__global__ __launch_bounds__(512, 2)
void k_gemm8(const unsigned short* __restrict__ A,
             const unsigned short* __restrict__ Bt,
             const float* __restrict__ bias,
             unsigned short* __restrict__ Qb,
             unsigned short* __restrict__ Kb,
             unsigned short* __restrict__ Vt,
             float* __restrict__ out) {
    constexpr int BN  = (MODE == 0) ? 192 : 128;
    constexpr int NF  = BN / 64;               // N-frags per wave (3 / 2)
    constexpr int NBN = (MODE == 0) ? 16 : 8;  // n-blocks
    constexpr int NWG = (MODE == 0) ? 512 : 256;  // both % 256 == 0: no round tail
    constexpr int NT  = KD / 64;               // 16 K-tiles
    constexpr int CHB = BN / 64;               // B chunks per wave per tile (3 / 2)

    __shared__ alignas(16) short As3[3 * 2 * 128 * 64];  // 96 KB
    __shared__ alignas(16) short Bs[2 * BN * 64];        // 48 / 32 KB

    const int tid = threadIdx.x;
    const int lane = tid & 63, wid = tid >> 6;
    const int quad = lane >> 4, l16 = lane & 15;
    const int wg_m = wid >> 2, wg_n = wid & 3;

    // XCD-bijective chunk (NWG % 8 == 0), then n-fastest decode (A panel L2-resident)
    const int id = ((int)blockIdx.x & 7) * (NWG >> 3) + ((int)blockIdx.x >> 3);
    const int mb = id / NBN, nb = id - mb * NBN;
    const int m0 = mb * 256, n0 = nb * BN;

    const int srow = lane >> 3;
    const int gcol = ((lane & 7) ^ srow) * 8;       // pre-swizzled global k-seg

    const unsigned short* Ag = A + (size_t)m0 * KD + gcol;
    const unsigned short* Bg = Bt + (size_t)n0 * KD + gcol;

    // stage one 128-row A half into region `reg` (2 gl_lds/wave)
    auto stA = [&](int kt, int h, int reg) {
#pragma unroll
        for (int c = 0; c < 2; c++) {
            const int rb = wid * 16 + c * 8;
            gl_lds16(Ag + (size_t)(h * 128 + rb + srow) * KD + kt * 64,
                     &As3[reg * 16384 + h * 8192 + rb * 64]);
        }
    };
    // stage full BN-row B tile into region `reg` (CHB gl_lds/wave, uniform chunks)
    auto stB = [&](int kt, int reg) {
#pragma unroll
        for (int c = 0; c < CHB; c++) {
            const int rb = (c * 8 + wid) * 8;
            gl_lds16(Bg + (size_t)(rb + srow) * KD + kt * 64,
                     &Bs[reg * (BN * 64) + rb * 64]);
        }
    };

    const int swz0 = ((quad) ^ (l16 & 7)) * 8;       // kc=0 read swizzle
    const int swz1 = ((4 + quad) ^ (l16 & 7)) * 8;   // kc=1 read swizzle
    const int bro = wg_n * (BN / 4);

    f32x4 acc[8][NF] = {};
    short8 af[4], bf0[NF], bf1[NF];

    // ---- prologue: A(0),B(0) then A(1),B(1); wait first tile only ----
    stA(0, 0, 0); stA(0, 1, 0); stB(0, 0);
    stA(1, 0, 1); stA(1, 1, 1); stB(1, 1);
    VM_WAIT_STEADY
    __builtin_amdgcn_s_barrier();

    // ---- main loop: stage kt+2 while computing kt ----
    int ca = 0;                                   // region of A(kt) = kt % 3
    for (int kt = 0; kt < NT - 2; kt++) {
        const int ca2 = (ca >= 1) ? ca - 1 : 2;   // (ca+2)%3
        const int par = kt & 1;
        GTILE(kt, ca, ca2, par, 1)
        ca = (ca >= 2) ? 0 : ca + 1;
    }
    // ---- tail: last two tiles, no staging ----
    GTILE(NT - 2, ca, 0, ((NT - 2) & 1), 0)
    ca = (ca >= 2) ? 0 : ca + 1;
    GTILE(NT - 1, ca, 0, ((NT - 1) & 1), 0)

    // ---- epilogue ----
#pragma unroll
    for (int nt = 0; nt < NF; nt++) {
        const int n = n0 + wg_n * (BN / 4) + nt * 16 + l16;
        const float bv = bias[n];
        if (MODE == 0) {
            const int sel = n >> 10;                  // 0=Q 1=K 2=V
            const int h = (n & 1023) >> 6;
            const int d = n & 63;
#pragma unroll
            for (int mt = 0; mt < 8; mt++)
#pragma unroll
                for (int r = 0; r < 4; r++) {
                    const int m = m0 + wg_m * 128 + mt * 16 + quad * 4 + r;
                    const int b = m >> 11, l = m & 2047;
                    const int bh = b * NH + h;
                    const float v = acc[mt][nt][r] + bv;
                    if (sel == 0)      Qb[(size_t)(bh * L + l) * 64 + d] = f2bf(v * 0.125f);
                    else if (sel == 1) Kb[(size_t)(bh * L + l) * 64 + d] = f2bf(v);
                    else               Vt[(size_t)(bh * 64 + d) * L + l] = f2bf(v);
                }
        } else {
#pragma unroll
            for (int mt = 0; mt < 8; mt++)
#pragma unroll
                for (int r = 0; r < 4; r++) {
                    const int m = m0 + wg_m * 128 + mt * 16 + quad * 4 + r;
                    out[(size_t)m * NE + n] = acc[mt][nt][r] + bv;
                }
        }
    }
}

// ---------- causal attention, static softmax, S^T formulation ----------
// grid (64, 16): block y -> qb = 15-y (LPT: heavy first). Block = 128 q rows,
// wave = 32 q rows, K/V tiles of 128. S^T = K Q^T puts P in C-layout with
// lane = q-col == B-operand shape (up to a k-permutation matched by V's
// A-operand). O^T in registers; LDS transpose restores coalesced stores.
// K LDS: seg^(row&7) swizzle; V LDS: seg^(row&15) swizzle. Both bank-clean.
__global__ __launch_bounds__(256, 4)
void k_attn(const unsigned short* __restrict__ Q,   // [BH][L][64], pre-scaled 1/8
            const unsigned short* __restrict__ Kb,  // [BH][L][64]
            const unsigned short* __restrict__ Vt,  // [BH][64][L]
            unsigned short* __restrict__ O) {       // [B][L][NE] bf16
    __shared__ alignas(16) short smem[16384];       // Ks[128*64] + Vs[64*128]; Os[128*72] overlays
    short* Ks = smem;
    short* Vs = smem + 8192;
    short* Os = smem;

    const int tid = threadIdx.x;
    const int lane = tid & 63, wid = tid >> 6;
    const int quad = lane >> 4, l16 = lane & 15;
    const int bh = blockIdx.x;
    const int qb = 15 - (int)blockIdx.y;             // heavy blocks first
    const int q0 = qb * 128 + wid * 32;
    const size_t base = (size_t)bh * L * 64;
    const int b = bh >> 4, h = bh & 15;

    const int srowK = lane >> 3;
    const int gsegK = (lane & 7) ^ srowK;            // K staging swizzle (row&7)
    const int vrow_off = (lane >> 4);                // V staging: 4 rows/instr
    const int vseg = lane & 15;

    short8 qf[2][2];
#pragma unroll
    for (int mt = 0; mt < 2; mt++)
#pragma unroll
        for (int dc = 0; dc < 2; dc++)
            qf[mt][dc] = *(const short8*)&Q[base + (size_t)(q0 + mt * 16 + l16) * 64 + dc * 32 + quad * 8];

    f32x4 o[2][4] = {};
    float lrow[2] = {0.f, 0.f};

    for (int kt = 0; kt <= qb; kt++) {
        __syncthreads();
        // K tile 128x64, gl_lds, seg^(row&7)
#pragma unroll
        for (int c = 0; c < 4; c++) {
            const int rbase = c * 32 + wid * 8;
            gl_lds16(&Kb[base + (size_t)(kt * 128 + rbase + srowK) * 64 + gsegK * 8],
                     &Ks[rbase * 64]);
        }
        // V^T tile 64x128, gl_lds, seg^(row&15)
#pragma unroll
        for (int c = 0; c < 4; c++) {
            const int rbase = c * 16 + wid * 4;
            const int row = rbase + vrow_off;
            const int gs = vseg ^ (row & 15);
            gl_lds16(&Vt[base + (size_t)row * L + kt * 128 + gs * 8], &Vs[rbase * 128]);
        }
        __syncthreads();

        const bool diag = (kt == qb);
        const int chunks = diag ? (wid + 1) : 4;

        for (int kc = 0; kc < chunks; kc++) {
            // K fragments (A-operand rows = k)
            short8 kf[2][2];
#pragma unroll
            for (int j0 = 0; j0 < 2; j0++)
#pragma unroll
                for (int dc = 0; dc < 2; dc++) {
                    const int R = kc * 32 + j0 * 16 + l16;
                    kf[j0][dc] = *(const short8*)&Ks[R * 64 + (((dc * 4 + quad) ^ (R & 7)) * 8)];
                }
            // S^T[k][q]
            f32x4 st[2][2];
#pragma unroll
            for (int mt = 0; mt < 2; mt++)
#pragma unroll
                for (int j0 = 0; j0 < 2; j0++) {
                    f32x4 z = {};
                    z = __builtin_amdgcn_mfma_f32_16x16x32_bf16(kf[j0][0], qf[mt][0], z, 0, 0, 0);
                    z = __builtin_amdgcn_mfma_f32_16x16x32_bf16(kf[j0][1], qf[mt][1], z, 0, 0, 0);
                    st[mt][j0] = z;
                }
            const bool dm = diag && (kc == wid);
            // p = exp(s); build B-operand frags in registers (k-permuted)
            short8 pb[2];
#pragma unroll
            for (int mt = 0; mt < 2; mt++) {
                float pe[8];
                float sum = 0.f;
#pragma unroll
                for (int j0 = 0; j0 < 2; j0++)
#pragma unroll
                    for (int r = 0; r < 4; r++) {
                        float p = __expf(st[mt][j0][r]);
                        if (dm) {
                            const int krel = j0 * 16 + quad * 4 + r;
                            const int qrel = mt * 16 + l16;
                            if (krel > qrel) p = 0.f;
                        }
                        sum += p;
                        pe[j0 * 4 + r] = p;
                    }
                lrow[mt] += sum;
#pragma unroll
                for (int w = 0; w < 4; w++) {
                    unsigned pk = pack_bf2(pe[2 * w], pe[2 * w + 1]);
                    pb[mt][2 * w] = (short)(pk & 0xffff);
                    pb[mt][2 * w + 1] = (short)(pk >> 16);
                }
            }
            // O^T += V^T P^T : A = V-frag (k-permuted to match pb)
#pragma unroll
            for (int dt = 0; dt < 4; dt++) {
                const int R2 = dt * 16 + l16;
                const int s16a = kc * 4 + (quad >> 1);
                const int off = (quad & 1) * 4;
                s16x4 lo = *(const s16x4*)&Vs[R2 * 128 + ((s16a ^ l16) * 8) + off];
                s16x4 hi = *(const s16x4*)&Vs[R2 * 128 + (((s16a + 2) ^ l16) * 8) + off];
                short8 vf = __builtin_shufflevector(lo, hi, 0, 1, 2, 3, 4, 5, 6, 7);
#pragma unroll
                for (int mt = 0; mt < 2; mt++)
                    o[mt][dt] = __builtin_amdgcn_mfma_f32_16x16x32_bf16(
                        vf, pb[mt], o[mt][dt], 0, 0, 0);
            }
        }
    }

    // denominators: sum over the 4 quads holding this q-column
    float inv[2];
#pragma unroll
    for (int mt = 0; mt < 2; mt++) {
        float rs = lrow[mt];
        rs += __shfl_xor(rs, 16);
        rs += __shfl_xor(rs, 32);
        inv[mt] = 1.0f / rs;
    }

    // O^T -> LDS transpose -> coalesced global store
    __syncthreads();
#pragma unroll
    for (int mt = 0; mt < 2; mt++) {
        const int ql = wid * 32 + mt * 16 + l16;
#pragma unroll
        for (int dt = 0; dt < 4; dt++) {
            unsigned w0 = f2bf(o[mt][dt][0] * inv[mt]) | (f2bf(o[mt][dt][1] * inv[mt]) << 16);
            unsigned w1 = f2bf(o[mt][dt][2] * inv[mt]) | (f2bf(o[mt][dt][3] * inv[mt]) << 16);
            *(uint2*)&Os[ql * 72 + dt * 16 + quad * 4] = make_uint2(w0, w1);
        }
    }
    __syncthreads();
#pragma unroll
    for (int i = 0; i < 4; i++) {
        const int id = i * 256 + tid;
        const int row = id >> 3, seg = id & 7;
        short8 v = *(const short8*)&Os[row * 72 + seg * 8];
        const int q = qb * 128 + row;
        *(short8*)&O[(size_t)(b * L + q) * NE + h * 64 + seg * 8] = v;
    }
}

extern "C" void kernel_launch(void* const* d_in, const int* in_sizes, int n_in,
                              void* d_out, int out_size, void* d_ws, size_t ws_size,
                              hipStream_t stream) {
    const float* x  = (const float*)d_in[0];
    const float* Wa = (const float*)d_in[1];
    const float* ba = (const float*)d_in[2];
    const float* Wp = (const float*)d_in[3];
    const float* bp = (const float*)d_in[4];
    float* out = (float*)d_out;

    char* ws = (char*)d_ws;
    unsigned short* xb  = (unsigned short*)(ws);                     // 16 MB; reused as O
    unsigned short* WaT = (unsigned short*)(ws + (16u << 20));       //  6 MB
    unsigned short* WpT = (unsigned short*)(ws + (22u << 20));       //  2 MB
    unsigned short* Qb  = (unsigned short*)(ws + (24u << 20));       // 16 MB [BH][L][64]
    unsigned short* Kb  = (unsigned short*)(ws + (40u << 20));       // 16 MB [BH][L][64]
    unsigned short* Vt  = (unsigned short*)(ws + (56u << 20));       // 16 MB [BH][64][L]

    k_f32_to_bf16<<<(M * NE / 8 + 255) / 256, 256, 0, stream>>>(x, xb, M * NE / 8);
    k_transpose_bf16<<<dim3(3 * NE / 32, NE / 32), dim3(32, 8), 0, stream>>>(Wa, WaT, NE, 3 * NE);
    k_transpose_bf16<<<dim3(NE / 32, NE / 32), dim3(32, 8), 0, stream>>>(Wp, WpT, NE, NE);

    k_gemm8<0><<<dim3(512), 512, 0, stream>>>(xb, WaT, ba, Qb, Kb, Vt, nullptr);

    unsigned short* Ob = xb;
    k_attn<<<dim3(NB * NH, 16), 256, 0, stream>>>(Qb, Kb, Vt, Ob);

    k_gemm8<1><<<dim3(256), 512, 0, stream>>>(Ob, WpT, bp, nullptr, nullptr, nullptr, out);
}

// Round 3
// 247.943 us; speedup vs baseline: 1.1002x; 1.1002x over previous
//
#include <hip/hip_runtime.h>

// MHA block on gfx950: qkv = x@Wa+ba; causal attention (static softmax); out = o@Wp+bp.
// B=4, L=2048, D=1024, H=16, Hd=64. bf16 MFMA 16x16x32, fp32 accumulation.
// R8: revert GEMM to the verified R5 128x128 structure (8-phase rebuild was
// stall-bound at 17-21% MfmaUtil over two rounds). Two isolated fixes:
//  (1) GEMM MODE0: persistent 2 tiles/block, grid 768 -> exactly 3 resident
//      blocks/CU, no 1.5-round tail (was 1536 blocks / 1024 slots). Tile pair
//      (t, t+768) shares the n-column -> B panel L2-hot. Inner loop unchanged.
//  (2) Attention: K/V double-buffered (64KB LDS, 2 blocks/CU). Tile kt+1's
//      8 gl_lds issued at top of iter kt after a raw s_barrier; waited with
//      vmcnt(0)+s_barrier a full iteration later (no __syncthreads drain in
//      the loop). setprio(1) around QK and PV MFMA clusters.

typedef __attribute__((ext_vector_type(8))) short short8;   // 8 bf16
typedef __attribute__((ext_vector_type(4))) short s16x4;    // 4 bf16
typedef __attribute__((ext_vector_type(4))) float f32x4;    // MFMA C/D frag

#define DEVI __device__ __forceinline__

constexpr int NE = 1024, NH = 16, NB = 4, L = 2048;
constexpr int M = NB * L;       // 8192 tokens
constexpr int KD = 1024;        // GEMM K (both GEMMs)

DEVI unsigned f2bf(float f) {
    union { float f; unsigned u; } v; v.f = f;
    unsigned u = v.u;
    u += 0x7fffu + ((u >> 16) & 1u);   // RNE
    return u >> 16;
}
DEVI unsigned pack_bf2(float lo, float hi) {   // round-half-up, 2 floats -> 1 dword
    union { float f; unsigned u; } a, b; a.f = lo; b.f = hi;
    return ((a.u + 0x8000u) >> 16) | ((b.u + 0x8000u) & 0xffff0000u);
}

typedef const __attribute__((address_space(1))) void* gas_t;
typedef __attribute__((address_space(3))) void* las_t;
DEVI void gl_lds16(const void* g, void* l) {
    __builtin_amdgcn_global_load_lds((gas_t)g, (las_t)l, 16, 0, 0);
}

// ---------- fp32 -> bf16 bulk convert (x) ----------
__global__ void k_f32_to_bf16(const float* __restrict__ in,
                              unsigned short* __restrict__ out, int n8) {
    int i = blockIdx.x * blockDim.x + threadIdx.x;
    if (i >= n8) return;
    const float4* p = (const float4*)in + (size_t)i * 2;
    float4 a = p[0], b = p[1];
    short8 r;
    r[0] = f2bf(a.x); r[1] = f2bf(a.y); r[2] = f2bf(a.z); r[3] = f2bf(a.w);
    r[4] = f2bf(b.x); r[5] = f2bf(b.y); r[6] = f2bf(b.z); r[7] = f2bf(b.w);
    ((short8*)out)[i] = r;
}

// ---------- fp32 [R][C] -> bf16 [C][R] transpose-convert (weights) ----------
__global__ void k_transpose_bf16(const float* __restrict__ in,
                                 unsigned short* __restrict__ out, int R, int C) {
    __shared__ float t[32][33];
    int x = blockIdx.x * 32 + threadIdx.x;
    int y0 = blockIdx.y * 32;
#pragma unroll
    for (int i = 0; i < 4; i++)
        t[threadIdx.y + 8 * i][threadIdx.x] = in[(size_t)(y0 + threadIdx.y + 8 * i) * C + x];
    __syncthreads();
    int xo = y0 + threadIdx.x;
    int yo = blockIdx.x * 32 + threadIdx.y;
#pragma unroll
    for (int i = 0; i < 4; i++)
        out[(size_t)(yo + 8 * i) * R + xo] = f2bf(t[threadIdx.x][threadIdx.y + 8 * i]);
}

// ---------- 128x128 bf16 GEMM, BK=64, swizzled LDS (R5 structure) ----------
// LDS slot s of row r holds global k-seg s^(r&7)  (seg = 16B = 8 bf16).
// Persistent: MODE0 grid 768 x 2 tiles (pair shares n-column); MODE1 grid 512 x 1.
template <int MODE>
__global__ __launch_bounds__(256, 4)
void k_gemm(const unsigned short* __restrict__ A,
            const unsigned short* __restrict__ Bt,
            const float* __restrict__ bias,
            unsigned short* __restrict__ Qb,
            unsigned short* __restrict__ Kb,
            unsigned short* __restrict__ Vt,
            float* __restrict__ out) {
    constexpr int NBN  = (MODE == 0) ? 24 : 8;     // n-blocks
    constexpr int GRID = (MODE == 0) ? 768 : 512;
    constexpr int REPS = (MODE == 0) ? 2 : 1;

    __shared__ alignas(16) short As[128 * 64];
    __shared__ alignas(16) short Bs[128 * 64];
    const int tid = threadIdx.x;
    const int lane = tid & 63, wid = tid >> 6;
    const int quad = lane >> 4, l16 = lane & 15;
    const int wm = (wid >> 1) * 64, wn = (wid & 1) * 64;

    const int srow = lane >> 3;              // 8 rows per wave-call
    const int gseg = (lane & 7) ^ srow;      // swizzled global seg

    // XCD-bijective swizzle (GRID % 8 == 0)
    const int p = (int)blockIdx.x;
    const int ps = (p & 7) * (GRID / 8) + (p >> 3);

    for (int rep = 0; rep < REPS; rep++) {
        const int t = ps + rep * GRID;
        const int n0 = (t % NBN) * 128;
        const int m0 = (t / NBN) * 128;

        f32x4 acc[4][4] = {};

        for (int kk = 0; kk < KD; kk += 64) {
            __syncthreads();
#pragma unroll
            for (int c = 0; c < 4; c++) {
                const int rbase = c * 32 + wid * 8;
                gl_lds16(&A[(size_t)(m0 + rbase + srow) * KD + kk + gseg * 8], &As[rbase * 64]);
                gl_lds16(&Bt[(size_t)(n0 + rbase + srow) * KD + kk + gseg * 8], &Bs[rbase * 64]);
            }
            __syncthreads();
#pragma unroll
            for (int kc = 0; kc < 2; kc++) {
                short8 af[4], bf[4];
#pragma unroll
                for (int tt = 0; tt < 4; tt++) {
                    const int Ra = wm + tt * 16 + l16;
                    af[tt] = *(const short8*)&As[Ra * 64 + (((kc * 4 + quad) ^ (Ra & 7)) * 8)];
                    const int Rb = wn + tt * 16 + l16;
                    bf[tt] = *(const short8*)&Bs[Rb * 64 + (((kc * 4 + quad) ^ (Rb & 7)) * 8)];
                }
#pragma unroll
                for (int mt = 0; mt < 4; mt++)
#pragma unroll
                    for (int nt = 0; nt < 4; nt++)
                        acc[mt][nt] = __builtin_amdgcn_mfma_f32_16x16x32_bf16(
                            af[mt], bf[nt], acc[mt][nt], 0, 0, 0);
            }
        }

#pragma unroll
        for (int nt = 0; nt < 4; nt++) {
            const int n = n0 + wn + nt * 16 + l16;
            const float bv = bias[n];
            if (MODE == 0) {
                const int sel = n >> 10;                  // 0=Q 1=K 2=V
                const int h = (n & 1023) >> 6;
                const int d = n & 63;
#pragma unroll
                for (int mt = 0; mt < 4; mt++)
#pragma unroll
                    for (int r = 0; r < 4; r++) {
                        const int m = m0 + wm + mt * 16 + quad * 4 + r;
                        const int b = m >> 11, l = m & 2047;
                        const int bh = b * NH + h;
                        const float v = acc[mt][nt][r] + bv;
                        if (sel == 0)      Qb[(size_t)(bh * L + l) * 64 + d] = f2bf(v * 0.125f);
                        else if (sel == 1) Kb[(size_t)(bh * L + l) * 64 + d] = f2bf(v);
                        else               Vt[(size_t)(bh * 64 + d) * L + l] = f2bf(v);
                    }
            } else {
#pragma unroll
                for (int mt = 0; mt < 4; mt++)
#pragma unroll
                    for (int r = 0; r < 4; r++) {
                        const int m = m0 + wm + mt * 16 + quad * 4 + r;
                        out[(size_t)m * NE + n] = acc[mt][nt][r] + bv;
                    }
            }
        }
    }
}

// ---------- causal attention, static softmax, S^T formulation ----------
// grid (64, 16): block y -> qb = 15-y (LPT: heavy first). Block = 128 q rows,
// wave = 32 q rows, K/V tiles of 128. S^T = K Q^T puts P in C-layout with
// lane = q-col == B-operand shape (up to a k-permutation matched by V's
// A-operand). O^T in registers; LDS transpose restores coalesced stores.
// R8: K/V double-buffered; tile kt+1 staged at top of iter kt (after raw
// s_barrier), waited vmcnt(0)+s_barrier a full iteration later. One barrier
// per iteration. K LDS: seg^(row&7); V LDS: seg^(row&15). Both bank-clean.
__global__ __launch_bounds__(256, 2)
void k_attn(const unsigned short* __restrict__ Q,   // [BH][L][64], pre-scaled 1/8
            const unsigned short* __restrict__ Kb,  // [BH][L][64]
            const unsigned short* __restrict__ Vt,  // [BH][64][L]
            unsigned short* __restrict__ O) {       // [B][L][NE] bf16
    __shared__ alignas(16) short smem[32768];       // Ks[2][8192] | Vs[2][8192]; Os[128*72] overlays
    short* Os = smem;

    const int tid = threadIdx.x;
    const int lane = tid & 63, wid = tid >> 6;
    const int quad = lane >> 4, l16 = lane & 15;
    const int bh = blockIdx.x;
    const int qb = 15 - (int)blockIdx.y;             // heavy blocks first
    const int q0 = qb * 128 + wid * 32;
    const size_t base = (size_t)bh * L * 64;
    const int b = bh >> 4, h = bh & 15;

    const int srowK = lane >> 3;
    const int gsegK = (lane & 7) ^ srowK;            // K staging swizzle (row&7)
    const int vrow_off = (lane >> 4);                // V staging: 4 rows/instr
    const int vseg = lane & 15;

    auto stK = [&](int kt, int buf) {
#pragma unroll
        for (int c = 0; c < 4; c++) {
            const int rbase = c * 32 + wid * 8;
            gl_lds16(&Kb[base + (size_t)(kt * 128 + rbase + srowK) * 64 + gsegK * 8],
                     &smem[buf * 8192 + rbase * 64]);
        }
    };
    auto stV = [&](int kt, int buf) {
#pragma unroll
        for (int c = 0; c < 4; c++) {
            const int rbase = c * 16 + wid * 4;
            const int row = rbase + vrow_off;
            const int gs = vseg ^ (row & 15);
            gl_lds16(&Vt[base + (size_t)row * L + kt * 128 + gs * 8],
                     &smem[16384 + buf * 8192 + rbase * 128]);
        }
    };

    short8 qf[2][2];
#pragma unroll
    for (int mt = 0; mt < 2; mt++)
#pragma unroll
        for (int dc = 0; dc < 2; dc++)
            qf[mt][dc] = *(const short8*)&Q[base + (size_t)(q0 + mt * 16 + l16) * 64 + dc * 32 + quad * 8];

    f32x4 o[2][4] = {};
    float lrow[2] = {0.f, 0.f};

    stK(0, 0); stV(0, 0);

    for (int kt = 0; kt <= qb; kt++) {
        // K(kt),V(kt) were issued a full iteration ago (or in prologue).
        asm volatile("s_waitcnt vmcnt(0)" ::: "memory");
        __builtin_amdgcn_s_barrier();
        // Buffers (kt+1)&1 are dead (readers finished before this barrier).
        if (kt < qb) { stK(kt + 1, (kt + 1) & 1); stV(kt + 1, (kt + 1) & 1); }

        const short* Ks = &smem[(kt & 1) * 8192];
        const short* Vs = &smem[16384 + (kt & 1) * 8192];

        const bool diag = (kt == qb);
        const int chunks = diag ? (wid + 1) : 4;

        for (int kc = 0; kc < chunks; kc++) {
            // K fragments (A-operand rows = k)
            short8 kf[2][2];
#pragma unroll
            for (int j0 = 0; j0 < 2; j0++)
#pragma unroll
                for (int dc = 0; dc < 2; dc++) {
                    const int R = kc * 32 + j0 * 16 + l16;
                    kf[j0][dc] = *(const short8*)&Ks[R * 64 + (((dc * 4 + quad) ^ (R & 7)) * 8)];
                }
            // S^T[k][q]
            f32x4 st[2][2];
            __builtin_amdgcn_s_setprio(1);
#pragma unroll
            for (int mt = 0; mt < 2; mt++)
#pragma unroll
                for (int j0 = 0; j0 < 2; j0++) {
                    f32x4 z = {};
                    z = __builtin_amdgcn_mfma_f32_16x16x32_bf16(kf[j0][0], qf[mt][0], z, 0, 0, 0);
                    z = __builtin_amdgcn_mfma_f32_16x16x32_bf16(kf[j0][1], qf[mt][1], z, 0, 0, 0);
                    st[mt][j0] = z;
                }
            __builtin_amdgcn_s_setprio(0);
            const bool dm = diag && (kc == wid);
            // p = exp(s); build B-operand frags in registers (k-permuted)
            short8 pb[2];
#pragma unroll
            for (int mt = 0; mt < 2; mt++) {
                float pe[8];
                float sum = 0.f;
#pragma unroll
                for (int j0 = 0; j0 < 2; j0++)
#pragma unroll
                    for (int r = 0; r < 4; r++) {
                        float p = __expf(st[mt][j0][r]);
                        if (dm) {
                            const int krel = j0 * 16 + quad * 4 + r;
                            const int qrel = mt * 16 + l16;
                            if (krel > qrel) p = 0.f;
                        }
                        sum += p;
                        pe[j0 * 4 + r] = p;
                    }
                lrow[mt] += sum;
#pragma unroll
                for (int w = 0; w < 4; w++) {
                    unsigned pk = pack_bf2(pe[2 * w], pe[2 * w + 1]);
                    pb[mt][2 * w] = (short)(pk & 0xffff);
                    pb[mt][2 * w + 1] = (short)(pk >> 16);
                }
            }
            // O^T += V^T P^T : A = V-frag (k-permuted to match pb)
#pragma unroll
            for (int dt = 0; dt < 4; dt++) {
                const int R2 = dt * 16 + l16;
                const int s16a = kc * 4 + (quad >> 1);
                const int off = (quad & 1) * 4;
                s16x4 lo = *(const s16x4*)&Vs[R2 * 128 + ((s16a ^ l16) * 8) + off];
                s16x4 hi = *(const s16x4*)&Vs[R2 * 128 + (((s16a + 2) ^ l16) * 8) + off];
                short8 vf = __builtin_shufflevector(lo, hi, 0, 1, 2, 3, 4, 5, 6, 7);
                __builtin_amdgcn_s_setprio(1);
#pragma unroll
                for (int mt = 0; mt < 2; mt++)
                    o[mt][dt] = __builtin_amdgcn_mfma_f32_16x16x32_bf16(
                        vf, pb[mt], o[mt][dt], 0, 0, 0);
                __builtin_amdgcn_s_setprio(0);
            }
        }
    }

    // denominators: sum over the 4 quads holding this q-column
    float inv[2];
#pragma unroll
    for (int mt = 0; mt < 2; mt++) {
        float rs = lrow[mt];
        rs += __shfl_xor(rs, 16);
        rs += __shfl_xor(rs, 32);
        inv[mt] = 1.0f / rs;
    }

    // O^T -> LDS transpose -> coalesced global store
    __syncthreads();
#pragma unroll
    for (int mt = 0; mt < 2; mt++) {
        const int ql = wid * 32 + mt * 16 + l16;
#pragma unroll
        for (int dt = 0; dt < 4; dt++) {
            unsigned w0 = f2bf(o[mt][dt][0] * inv[mt]) | (f2bf(o[mt][dt][1] * inv[mt]) << 16);
            unsigned w1 = f2bf(o[mt][dt][2] * inv[mt]) | (f2bf(o[mt][dt][3] * inv[mt]) << 16);
            *(uint2*)&Os[ql * 72 + dt * 16 + quad * 4] = make_uint2(w0, w1);
        }
    }
    __syncthreads();
#pragma unroll
    for (int i = 0; i < 4; i++) {
        const int id = i * 256 + tid;
        const int row = id >> 3, seg = id & 7;
        short8 v = *(const short8*)&Os[row * 72 + seg * 8];
        const int q = qb * 128 + row;
        *(short8*)&O[(size_t)(b * L + q) * NE + h * 64 + seg * 8] = v;
    }
}

extern "C" void kernel_launch(void* const* d_in, const int* in_sizes, int n_in,
                              void* d_out, int out_size, void* d_ws, size_t ws_size,
                              hipStream_t stream) {
    const float* x  = (const float*)d_in[0];
    const float* Wa = (const float*)d_in[1];
    const float* ba = (const float*)d_in[2];
    const float* Wp = (const float*)d_in[3];
    const float* bp = (const float*)d_in[4];
    float* out = (float*)d_out;

    char* ws = (char*)d_ws;
    unsigned short* xb  = (unsigned short*)(ws);                     // 16 MB; reused as O
    unsigned short* WaT = (unsigned short*)(ws + (16u << 20));       //  6 MB
    unsigned short* WpT = (unsigned short*)(ws + (22u << 20));       //  2 MB
    unsigned short* Qb  = (unsigned short*)(ws + (24u << 20));       // 16 MB [BH][L][64]
    unsigned short* Kb  = (unsigned short*)(ws + (40u << 20));       // 16 MB [BH][L][64]
    unsigned short* Vt  = (unsigned short*)(ws + (56u << 20));       // 16 MB [BH][64][L]

    k_f32_to_bf16<<<(M * NE / 8 + 255) / 256, 256, 0, stream>>>(x, xb, M * NE / 8);
    k_transpose_bf16<<<dim3(3 * NE / 32, NE / 32), dim3(32, 8), 0, stream>>>(Wa, WaT, NE, 3 * NE);
    k_transpose_bf16<<<dim3(NE / 32, NE / 32), dim3(32, 8), 0, stream>>>(Wp, WpT, NE, NE);

    k_gemm<0><<<dim3(768), 256, 0, stream>>>(xb, WaT, ba, Qb, Kb, Vt, nullptr);

    unsigned short* Ob = xb;
    k_attn<<<dim3(NB * NH, 16), 256, 0, stream>>>(Qb, Kb, Vt, Ob);

    k_gemm<1><<<dim3(512), 256, 0, stream>>>(Ob, WpT, bp, nullptr, nullptr, nullptr, out);
}